// Round 11
// baseline (1240.091 us; speedup 1.0000x reference)
//
#include <hip/hip_runtime.h>
#include <cstdint>
#include <cstddef>

#define HDIM 2048
#define IDIM 5504
#define NEXP 8
#define NTOK 4096
#define NROWS (2 * NTOK)

#define NCT1 86                      // IDIM/64 h-col tiles
#define NRT1 10                      // 1280-row capacity/expert (buckets ~1024±30)
#define NWG1 (NCT1 * NRT1 * NEXP)    // 6880, %8==0
#define NK1  (HDIM / 32)             // 64 K-steps
#define NCT2 16                      // HDIM/128 col tiles
#define NRT2 10
#define NWG2 (NCT2 * NRT2 * NEXP)    // 1280, %8==0
#define NK2  (IDIM / 32)             // 172 K-steps

typedef _Float16 half8 __attribute__((ext_vector_type(8)));
typedef _Float16 half4v __attribute__((ext_vector_type(4)));
typedef float floatx4 __attribute__((ext_vector_type(4)));

#define GLOAD16(g, l)                                                         \
  __builtin_amdgcn_global_load_lds(                                           \
      (const __attribute__((address_space(1))) void*)(g),                     \
      (__attribute__((address_space(3))) void*)(l), 16, 0, 0)

#define SBAR()   asm volatile("s_barrier" ::: "memory")
#define VMCNT4() asm volatile("s_waitcnt vmcnt(4)" ::: "memory")
#define LGKM0()  asm volatile("s_waitcnt lgkmcnt(0)" ::: "memory")

// ---------------- workspace layout (bytes) ----------------
#define XH_OFF   0                                    // fp16 x  [4096][2048]   16 MB
#define HB_OFF   (XH_OFF + (size_t)NTOK * HDIM * 2)   // fp16 h  [8192][5504]   90 MB
#define BTOK_OFF (HB_OFF + (size_t)NROWS * IDIM * 2)  // int  [8192]
#define BW_OFF   (BTOK_OFF + 32768)                   // float[8192]
#define TOKP_OFF (BW_OFF + 32768)                     // int  [4096]
#define TOKW_OFF (TOKP_OFF + 16384)                   // float2[4096]
#define T2R_OFF  (TOKW_OFF + 32768)                   // int  [8192]
#define META_OFF (T2R_OFF + 32768)                    // int[32]
#define Y2_OFF   (META_OFF + 128)                     // fp16 y2 [8192][2048]   32 MB

// Paired-row swizzle (rows of 64 B, units of 2 rows = 128 B, 8 slots of 16 B):
//   element (row r, 16B-chunk q in [0,4)): u=r>>1; sc=(r&1)*4+q; L = u*8 + (sc^(u&7))
//   inverse (chunk L -> global): u=L>>3; sc=(L&7)^(u&7); r=2u+(sc>>2); q=sc&3
// Frag reads: 2 lanes per 16B slot per quarter-wave = free; measured 0 conflicts (r3-r10).
//
// Counted-vmcnt 2-phase ledger (per K-step t):
//   astage(t+1)        -> queue [B(t+1)x4, A(t+1)x2]
//   compute(t)         (LDS only)
//   bwrite(B(t+1))     compiler auto-waits B(t+1) -> vmcnt(2), leaves A(t+1)
//   bload(t+2)         -> queue [A(t+1)x2, B(t+2)x4]
//   VMCNT(4)           certifies A(t+1); B(t+2)x4 SPAN the barrier (never drained)
//   LGKM0 + SBAR       ds_write visibility; no vmcnt(0) drain

// ---------------- small kernels ----------------
__global__ void cvt_x_kernel(const float4* __restrict__ x, half4v* __restrict__ xh, int n4) {
  int i = blockIdx.x * blockDim.x + threadIdx.x;
  int st = gridDim.x * blockDim.x;
  for (; i < n4; i += st) {
    float4 v = x[i];
    half4v o = { (_Float16)v.x, (_Float16)v.y, (_Float16)v.z, (_Float16)v.w };
    xh[i] = o;
  }
}

__global__ void router_kernel(const float* __restrict__ x, const float* __restrict__ rw,
                              int* __restrict__ tokp, float2* __restrict__ tokw,
                              int* __restrict__ cnt) {
  int t = blockIdx.x * 4 + (threadIdx.x >> 6);
  int lane = threadIdx.x & 63;
  const float4* xr = (const float4*)(x + (size_t)t * HDIM);
  float acc[NEXP];
#pragma unroll
  for (int e = 0; e < NEXP; ++e) acc[e] = 0.f;
#pragma unroll
  for (int it = 0; it < HDIM / 256; ++it) {
    float4 xv = xr[lane + 64 * it];
#pragma unroll
    for (int e = 0; e < NEXP; ++e) {
      float4 wv = ((const float4*)(rw + (size_t)e * HDIM))[lane + 64 * it];
      acc[e] += xv.x * wv.x + xv.y * wv.y + xv.z * wv.z + xv.w * wv.w;
    }
  }
#pragma unroll
  for (int off = 32; off > 0; off >>= 1) {
#pragma unroll
    for (int e = 0; e < NEXP; ++e) acc[e] += __shfl_xor(acc[e], off);
  }
  if (lane == 0) {
    int e0 = 0; float v0 = acc[0];
#pragma unroll
    for (int e = 1; e < NEXP; ++e) {
      if (acc[e] > v0) { v0 = acc[e]; e0 = e; }   // strict > : lowest idx on tie (lax.top_k)
    }
    int e1 = -1; float v1 = -3.0e38f;
#pragma unroll
    for (int e = 0; e < NEXP; ++e) {
      if (e == e0) continue;
      if (acc[e] > v1) { v1 = acc[e]; e1 = e; }
    }
    float w0 = 1.f / (1.f + __expf(v1 - v0));     // softmax over top-2 (v0 >= v1, stable)
    tokp[t] = e0 | (e1 << 8);
    tokw[t] = make_float2(w0, 1.f - w0);
    atomicAdd(&cnt[e0], 1);
    atomicAdd(&cnt[e1], 1);
  }
}

__global__ void scan_kernel(const int* __restrict__ cnt, int* __restrict__ offp) {
  if (threadIdx.x == 0) {
    int s = 0;
    for (int e = 0; e < NEXP; ++e) { offp[e] = s; s += cnt[e]; }
    offp[NEXP] = s;
  }
}

__global__ void scatter_kernel(const int* __restrict__ tokp, const float2* __restrict__ tokw,
                               const int* __restrict__ offp, int* __restrict__ cursor,
                               int* __restrict__ btok, float* __restrict__ bw,
                               int* __restrict__ t2r) {
  int t = blockIdx.x * blockDim.x + threadIdx.x;
  if (t >= NTOK) return;
  int p = tokp[t];
  float2 w = tokw[t];
  int e0 = p & 0xff, e1 = (p >> 8) & 0xff;
  int r0 = offp[e0] + atomicAdd(&cursor[e0], 1);
  btok[r0] = t; bw[r0] = w.x; t2r[2 * t] = r0;
  int r1 = offp[e1] + atomicAdd(&cursor[e1], 1);
  btok[r1] = t; bw[r1] = w.y; t2r[2 * t + 1] = r1;
}

__global__ void combine_kernel(const _Float16* __restrict__ y2, const int* __restrict__ t2r,
                               const float2* __restrict__ tokw, float* __restrict__ out) {
  int idx = blockIdx.x * 256 + threadIdx.x;      // 4096 * 512
  int t = idx >> 9, c = (idx & 511) * 4;
  int r0 = t2r[2 * t], r1 = t2r[2 * t + 1];
  float2 w = tokw[t];
  half4v v0 = *(const half4v*)(y2 + (size_t)r0 * HDIM + c);
  half4v v1 = *(const half4v*)(y2 + (size_t)r1 * HDIM + c);
  float4 o;
  o.x = w.x * (float)v0[0] + w.y * (float)v1[0];
  o.y = w.x * (float)v0[1] + w.y * (float)v1[1];
  o.z = w.x * (float)v0[2] + w.y * (float)v1[2];
  o.w = w.x * (float)v0[3] + w.y * (float)v1[3];
  *(float4*)(out + (size_t)t * HDIM + c) = o;
}

// ---------------- stage 1: h = silu(X Wg^T) * (X Wu^T) ----------------
// BM=128, B-rows=128 (64 Wg + 64 Wu), BK=32, 4 waves (2Mx2N), fp16 LDS 32 KB.
// A via global_load_lds (t+1 ahead); B fp32->reg (t+2 ahead, ping-pong bpE/bpO)
// ->cvt->ds_write. Counted-vmcnt: B(t+2) loads span the barrier (no vmcnt(0) drain).
__global__ __launch_bounds__(256, 3) void stage1_kernel(
    const _Float16* __restrict__ xh, const float* __restrict__ Wg, const float* __restrict__ Wu,
    const int* __restrict__ offp, const int* __restrict__ btok, _Float16* __restrict__ hb) {
  int bid = blockIdx.x;
  int wg = (bid & 7) * (NWG1 / 8) + (bid >> 3);    // bijective: XCD k <-> expert k
  int rt = wg % NRT1;
  int ct = (wg / NRT1) % NCT1;
  int e  = wg / (NRT1 * NCT1);
  int base = offp[e];
  int ne = offp[e + 1] - base;
  if (rt * 128 >= ne) return;
  int valid = ne - rt * 128; if (valid > 128) valid = 128;
  int tid = threadIdx.x, lane = tid & 63, wave = tid >> 6;

  __shared__ __attribute__((aligned(16))) _Float16 As[2][128 * 32];   // 2 x 8 KB
  __shared__ __attribute__((aligned(16))) _Float16 Bs[2][128 * 32];   // 2 x 8 KB

  const char* abase = (const char*)xh;
  uint32_t aoffB[2];
  const float* bsrc[2];
  int bdstB[2];
  size_t eoff = (size_t)e * IDIM * HDIM;
#pragma unroll
  for (int i = 0; i < 2; ++i) {
    int L = wave * 128 + i * 64 + lane;
    int u = L >> 3, sc = (L & 7) ^ (u & 7);
    int r = 2 * u + (sc >> 2), q = sc & 3;
    int rr = (r < valid) ? r : (valid - 1);
    aoffB[i] = (uint32_t)(((uint32_t)btok[base + rt * 128 + rr] * HDIM + q * 8) * 2);
    const float* rp = (r < 64) ? (Wg + eoff + (size_t)(ct * 64 + r) * HDIM)
                               : (Wu + eoff + (size_t)(ct * 64 + (r - 64)) * HDIM);
    bsrc[i] = rp + q * 8;
    bdstB[i] = L * 16;
  }
  int adst0 = __builtin_amdgcn_readfirstlane(wave * 2048);

  int wm = wave >> 1, wn = wave & 1;
  int lrow = lane & 15, kg = lane >> 4;

  int aoff[4], boff[4];
#pragma unroll
  for (int mi = 0; mi < 4; ++mi) {
    int r = wm * 64 + mi * 16 + lrow;
    int u = r >> 1, cc = (r & 1) * 4 + kg;
    aoff[mi] = u * 64 + ((cc ^ (u & 7)) * 8);
  }
#pragma unroll
  for (int f = 0; f < 4; ++f) {
    int rb = (f < 2) ? (wn * 32 + f * 16 + lrow) : (64 + wn * 32 + (f - 2) * 16 + lrow);
    int u = rb >> 1, cc = (rb & 1) * 4 + kg;
    boff[f] = u * 64 + ((cc ^ (u & 7)) * 8);
  }

  floatx4 acc[4][4] = {};   // [mi][f]: f 0-1 = gate, 2-3 = up
  floatx4 bpE[2][2], bpO[2][2];

  auto bload = [&](int t, floatx4 (&bp)[2][2]) {
    int tc = (t < NK1) ? t : NK1 - 1;
#pragma unroll
    for (int i = 0; i < 2; ++i) {
      bp[i][0] = *(const floatx4*)(bsrc[i] + tc * 32);
      bp[i][1] = *(const floatx4*)(bsrc[i] + tc * 32 + 4);
    }
  };
  auto astage = [&](int t, int buf) {
    int tc = (t < NK1) ? t : NK1 - 1;
    uint32_t kb = (uint32_t)tc * 64u;
#pragma unroll
    for (int i = 0; i < 2; ++i)
      GLOAD16(abase + (aoffB[i] + kb), (char*)As[buf] + adst0 + i * 1024);
  };
  auto bwrite = [&](floatx4 (&bp)[2][2], int buf) {
#pragma unroll
    for (int i = 0; i < 2; ++i) {
      half8 h = { (_Float16)bp[i][0].x, (_Float16)bp[i][0].y, (_Float16)bp[i][0].z, (_Float16)bp[i][0].w,
                  (_Float16)bp[i][1].x, (_Float16)bp[i][1].y, (_Float16)bp[i][1].z, (_Float16)bp[i][1].w };
      *(half8*)((char*)Bs[buf] + bdstB[i]) = h;
    }
  };
  auto compute = [&](int abuf, int bbuf) {
    half8 af[4], bf[4];
#pragma unroll
    for (int mi = 0; mi < 4; ++mi) af[mi] = *(const half8*)&As[abuf][aoff[mi]];
#pragma unroll
    for (int f = 0; f < 4; ++f) bf[f] = *(const half8*)&Bs[bbuf][boff[f]];
#pragma unroll
    for (int mi = 0; mi < 4; ++mi)
#pragma unroll
      for (int f = 0; f < 4; ++f)
        acc[mi][f] = __builtin_amdgcn_mfma_f32_16x16x32_f16(af[mi], bf[f], acc[mi][f], 0, 0, 0);
  };

  // Prologue: A0 DMA, B0+B1 reg loads, B0 -> LDS (auto-waits B0, and A0 with it).
  astage(0, 0);
  bload(0, bpE);
  bload(1, bpO);
  bwrite(bpE, 0);
  LGKM0(); SBAR();

  for (int I = 0; I < NK1 / 2; ++I) {
    int t0 = 2 * I, t1 = 2 * I + 1;
    astage(t0 + 1, 1);
    compute(0, 0);
    bwrite(bpO, 1);          // auto-waits B(t0+1); leaves A(t0+1) in flight
    bload(t0 + 2, bpE);
    VMCNT4(); LGKM0(); SBAR();   // certify A(t0+1); B(t0+2)x4 span the barrier
    astage(t1 + 1, 0);
    compute(1, 1);
    bwrite(bpE, 0);
    bload(t1 + 2, bpO);
    VMCNT4(); LGKM0(); SBAR();
  }

  size_t hrow_base = (size_t)(base + rt * 128);
#pragma unroll
  for (int mi = 0; mi < 4; ++mi) {
#pragma unroll
    for (int j = 0; j < 4; ++j) {
      int r = wm * 64 + mi * 16 + kg * 4 + j;   // C/D: row=(lane>>4)*4+reg, col=lane&15
      if (r < valid) {
#pragma unroll
        for (int f = 0; f < 2; ++f) {
          float g = acc[mi][f][j], u = acc[mi][f + 2][j];
          float hv = g / (1.f + __expf(-g)) * u;   // silu(g)*u
          int c = ct * 64 + wn * 32 + f * 16 + lrow;
          hb[(hrow_base + r) * IDIM + c] = (_Float16)hv;
        }
      }
    }
  }
}

// ---------------- stage 2: y = h Wd^T (per bucket row) ----------------
// Same counted-vmcnt pipeline. Stores fp16 y2 rows; combine mixes top-2.
__global__ __launch_bounds__(256, 3) void stage2_kernel(
    const _Float16* __restrict__ hb, const float* __restrict__ Wd,
    const int* __restrict__ offp, _Float16* __restrict__ y2) {
  int bid = blockIdx.x;
  int wg = (bid & 7) * (NWG2 / 8) + (bid >> 3);
  int rt = wg % NRT2;
  int ct = (wg / NRT2) % NCT2;
  int e  = wg / (NRT2 * NCT2);
  int base = offp[e];
  int ne = offp[e + 1] - base;
  if (rt * 128 >= ne) return;
  int valid = ne - rt * 128; if (valid > 128) valid = 128;
  int tid = threadIdx.x, lane = tid & 63, wave = tid >> 6;

  __shared__ __attribute__((aligned(16))) _Float16 As[2][128 * 32];
  __shared__ __attribute__((aligned(16))) _Float16 Bs[2][128 * 32];

  const char* abase = (const char*)hb;
  uint32_t aoffB[2];
  const float* bsrc[2];
  int bdstB[2];
  const float* wdE = Wd + (size_t)e * HDIM * IDIM;
#pragma unroll
  for (int i = 0; i < 2; ++i) {
    int L = wave * 128 + i * 64 + lane;
    int u = L >> 3, sc = (L & 7) ^ (u & 7);
    int r = 2 * u + (sc >> 2), q = sc & 3;
    int rr = (r < valid) ? r : (valid - 1);
    aoffB[i] = (uint32_t)(((size_t)(base + rt * 128 + rr) * IDIM + (size_t)q * 8) * 2);
    bsrc[i] = wdE + (size_t)(ct * 128 + r) * IDIM + q * 8;
    bdstB[i] = L * 16;
  }
  int adst0 = __builtin_amdgcn_readfirstlane(wave * 2048);

  int wm = wave >> 1, wn = wave & 1;
  int lrow = lane & 15, kg = lane >> 4;

  int aoff[4], boff[4];
#pragma unroll
  for (int mi = 0; mi < 4; ++mi) {
    int r = wm * 64 + mi * 16 + lrow;
    int u = r >> 1, cc = (r & 1) * 4 + kg;
    aoff[mi] = u * 64 + ((cc ^ (u & 7)) * 8);
  }
#pragma unroll
  for (int f = 0; f < 4; ++f) {
    int rb = wn * 64 + f * 16 + lrow;
    int u = rb >> 1, cc = (rb & 1) * 4 + kg;
    boff[f] = u * 64 + ((cc ^ (u & 7)) * 8);
  }

  floatx4 acc[4][4] = {};
  floatx4 bpE[2][2], bpO[2][2];

  auto bload = [&](int t, floatx4 (&bp)[2][2]) {
    int tc = (t < NK2) ? t : NK2 - 1;
#pragma unroll
    for (int i = 0; i < 2; ++i) {
      bp[i][0] = *(const floatx4*)(bsrc[i] + tc * 32);
      bp[i][1] = *(const floatx4*)(bsrc[i] + tc * 32 + 4);
    }
  };
  auto astage = [&](int t, int buf) {
    int tc = (t < NK2) ? t : NK2 - 1;
    uint32_t kb = (uint32_t)tc * 64u;
#pragma unroll
    for (int i = 0; i < 2; ++i)
      GLOAD16(abase + (aoffB[i] + kb), (char*)As[buf] + adst0 + i * 1024);
  };
  auto bwrite = [&](floatx4 (&bp)[2][2], int buf) {
#pragma unroll
    for (int i = 0; i < 2; ++i) {
      half8 h = { (_Float16)bp[i][0].x, (_Float16)bp[i][0].y, (_Float16)bp[i][0].z, (_Float16)bp[i][0].w,
                  (_Float16)bp[i][1].x, (_Float16)bp[i][1].y, (_Float16)bp[i][1].z, (_Float16)bp[i][1].w };
      *(half8*)((char*)Bs[buf] + bdstB[i]) = h;
    }
  };
  auto compute = [&](int abuf, int bbuf) {
    half8 af[4], bf[4];
#pragma unroll
    for (int mi = 0; mi < 4; ++mi) af[mi] = *(const half8*)&As[abuf][aoff[mi]];
#pragma unroll
    for (int f = 0; f < 4; ++f) bf[f] = *(const half8*)&Bs[bbuf][boff[f]];
#pragma unroll
    for (int mi = 0; mi < 4; ++mi)
#pragma unroll
      for (int f = 0; f < 4; ++f)
        acc[mi][f] = __builtin_amdgcn_mfma_f32_16x16x32_f16(af[mi], bf[f], acc[mi][f], 0, 0, 0);
  };

  astage(0, 0);
  bload(0, bpE);
  bload(1, bpO);
  bwrite(bpE, 0);
  LGKM0(); SBAR();

  for (int I = 0; I < NK2 / 2; ++I) {
    int t0 = 2 * I, t1 = 2 * I + 1;
    astage(t0 + 1, 1);
    compute(0, 0);
    bwrite(bpO, 1);
    bload(t0 + 2, bpE);
    VMCNT4(); LGKM0(); SBAR();
    astage(t1 + 1, 0);
    compute(1, 1);
    bwrite(bpE, 0);
    bload(t1 + 2, bpO);
    VMCNT4(); LGKM0(); SBAR();
  }

#pragma unroll
  for (int mi = 0; mi < 4; ++mi) {
#pragma unroll
    for (int j = 0; j < 4; ++j) {
      int r = wm * 64 + mi * 16 + kg * 4 + j;
      if (r < valid) {
        int grow = base + rt * 128 + r;
#pragma unroll
        for (int f = 0; f < 4; ++f) {
          int c = ct * 128 + wn * 64 + f * 16 + lrow;
          y2[(size_t)grow * HDIM + c] = (_Float16)acc[mi][f][j];
        }
      }
    }
  }
}

// ---------------- launch ----------------
extern "C" void kernel_launch(void* const* d_in, const int* in_sizes, int n_in,
                              void* d_out, int out_size, void* d_ws, size_t ws_size,
                              hipStream_t stream) {
  const float* x  = (const float*)d_in[0];
  const float* rw = (const float*)d_in[1];
  const float* Wg = (const float*)d_in[2];
  const float* Wu = (const float*)d_in[3];
  const float* Wd = (const float*)d_in[4];
  float* out = (float*)d_out;

  char* ws = (char*)d_ws;
  _Float16* xh  = (_Float16*)(ws + XH_OFF);
  _Float16* hb  = (_Float16*)(ws + HB_OFF);
  int*      btok = (int*)(ws + BTOK_OFF);
  float*    bwv  = (float*)(ws + BW_OFF);
  int*      tokp = (int*)(ws + TOKP_OFF);
  float2*   tokw = (float2*)(ws + TOKW_OFF);
  int*      t2r  = (int*)(ws + T2R_OFF);
  int*      meta = (int*)(ws + META_OFF);
  _Float16* y2   = (_Float16*)(ws + Y2_OFF);
  int* cnt = meta;          // [8]
  int* offp = meta + 8;     // [9]
  int* cursor = meta + 20;  // [8]

  hipMemsetAsync(meta, 0, 128, stream);

  cvt_x_kernel<<<2048, 256, 0, stream>>>((const float4*)x, (half4v*)xh, NTOK * HDIM / 4);
  router_kernel<<<NTOK / 4, 256, 0, stream>>>(x, rw, tokp, tokw, cnt);
  scan_kernel<<<1, 64, 0, stream>>>(cnt, offp);
  scatter_kernel<<<NTOK / 256, 256, 0, stream>>>(tokp, tokw, offp, cursor, btok, bwv, t2r);

  stage1_kernel<<<NWG1, 256, 0, stream>>>(xh, Wg, Wu, offp, btok, hb);
  stage2_kernel<<<NWG2, 256, 0, stream>>>(hb, Wd, offp, y2);
  combine_kernel<<<NTOK * HDIM / 4 / 256, 256, 0, stream>>>(y2, t2r, tokw, out);
}

// Round 12
// 1155.385 us; speedup vs baseline: 1.0733x; 1.0733x over previous
//
#include <hip/hip_runtime.h>
#include <cstdint>
#include <cstddef>

#define HDIM 2048
#define IDIM 5504
#define NEXP 8
#define NTOK 4096
#define NROWS (2 * NTOK)

#define NCT1 86                      // IDIM/64 h-col tiles
#define NRT1 10                      // 1280-row capacity/expert (buckets ~1024±30)
#define NWG1 (NCT1 * NRT1 * NEXP)    // 6880, %8==0
#define NK1  (HDIM / 32)             // 64 K-steps
#define NCT2 16                      // HDIM/128 col tiles
#define NRT2 10
#define NWG2 (NCT2 * NRT2 * NEXP)    // 1280, %8==0
#define NK2  (IDIM / 32)             // 172 K-steps

typedef _Float16 half8 __attribute__((ext_vector_type(8)));
typedef _Float16 half4v __attribute__((ext_vector_type(4)));
typedef float floatx4 __attribute__((ext_vector_type(4)));

#define GLOAD16(g, l)                                                         \
  __builtin_amdgcn_global_load_lds(                                           \
      (const __attribute__((address_space(1))) void*)(g),                     \
      (__attribute__((address_space(3))) void*)(l), 16, 0, 0)

// ---------------- workspace layout (bytes) ----------------
#define XH_OFF   0                                    // fp16 x  [4096][2048]   16 MB
#define HB_OFF   (XH_OFF + (size_t)NTOK * HDIM * 2)   // fp16 h  [8192][5504]   90 MB
#define BTOK_OFF (HB_OFF + (size_t)NROWS * IDIM * 2)  // int  [8192]
#define BW_OFF   (BTOK_OFF + 32768)                   // float[8192]
#define TOKP_OFF (BW_OFF + 32768)                     // int  [4096]
#define TOKW_OFF (TOKP_OFF + 16384)                   // float2[4096]
#define T2R_OFF  (TOKW_OFF + 32768)                   // int  [8192]
#define META_OFF (T2R_OFF + 32768)                    // int[32]
#define Y2_OFF   (META_OFF + 128)                     // fp16 y2 [8192][2048]   32 MB
#define WD16_OFF (Y2_OFF + (size_t)NROWS * HDIM * 2)  // fp16 Wd 180 MB

// Paired-row swizzle (rows of 64 B, units of 2 rows = 128 B, 8 slots of 16 B):
//   element (row r, 16B-chunk q in [0,4)): u=r>>1; sc=(r&1)*4+q; L = u*8 + (sc^(u&7))
//   inverse (chunk L -> global): u=L>>3; sc=(L&7)^(u&7); r=2u+(sc>>2); q=sc&3
// Frag reads: 2 lanes per 16B slot per quarter-wave = free; measured 0 conflicts (r3-r11).

// ---------------- small kernels ----------------
__global__ void cvt_w_kernel(const float4* __restrict__ w, half8* __restrict__ o, int n8) {
  int i = blockIdx.x * blockDim.x + threadIdx.x;
  int st = gridDim.x * blockDim.x;
  for (; i < n8; i += st) {
    float4 a = w[2 * i], b = w[2 * i + 1];
    o[i] = half8{ (_Float16)a.x, (_Float16)a.y, (_Float16)a.z, (_Float16)a.w,
                  (_Float16)b.x, (_Float16)b.y, (_Float16)b.z, (_Float16)b.w };
  }
}

// router + x->fp16 conversion fused (x is read once for logits; emit xh in the same pass)
__global__ void router_kernel(const float* __restrict__ x, const float* __restrict__ rw,
                              _Float16* __restrict__ xh,
                              int* __restrict__ tokp, float2* __restrict__ tokw,
                              int* __restrict__ cnt) {
  int t = blockIdx.x * 4 + (threadIdx.x >> 6);
  int lane = threadIdx.x & 63;
  const float4* xr = (const float4*)(x + (size_t)t * HDIM);
  _Float16* xhr = xh + (size_t)t * HDIM;
  float acc[NEXP];
#pragma unroll
  for (int e = 0; e < NEXP; ++e) acc[e] = 0.f;
#pragma unroll
  for (int it = 0; it < HDIM / 256; ++it) {
    float4 xv = xr[lane + 64 * it];
    half4v hv = { (_Float16)xv.x, (_Float16)xv.y, (_Float16)xv.z, (_Float16)xv.w };
    *(half4v*)(xhr + (lane + 64 * it) * 4) = hv;
#pragma unroll
    for (int e = 0; e < NEXP; ++e) {
      float4 wv = ((const float4*)(rw + (size_t)e * HDIM))[lane + 64 * it];
      acc[e] += xv.x * wv.x + xv.y * wv.y + xv.z * wv.z + xv.w * wv.w;
    }
  }
#pragma unroll
  for (int off = 32; off > 0; off >>= 1) {
#pragma unroll
    for (int e = 0; e < NEXP; ++e) acc[e] += __shfl_xor(acc[e], off);
  }
  if (lane == 0) {
    int e0 = 0; float v0 = acc[0];
#pragma unroll
    for (int e = 1; e < NEXP; ++e) {
      if (acc[e] > v0) { v0 = acc[e]; e0 = e; }   // strict > : lowest idx on tie (lax.top_k)
    }
    int e1 = -1; float v1 = -3.0e38f;
#pragma unroll
    for (int e = 0; e < NEXP; ++e) {
      if (e == e0) continue;
      if (acc[e] > v1) { v1 = acc[e]; e1 = e; }
    }
    float w0 = 1.f / (1.f + __expf(v1 - v0));     // softmax over top-2 (v0 >= v1, stable)
    tokp[t] = e0 | (e1 << 8);
    tokw[t] = make_float2(w0, 1.f - w0);
    atomicAdd(&cnt[e0], 1);
    atomicAdd(&cnt[e1], 1);
  }
}

__global__ void scan_kernel(const int* __restrict__ cnt, int* __restrict__ offp) {
  if (threadIdx.x == 0) {
    int s = 0;
    for (int e = 0; e < NEXP; ++e) { offp[e] = s; s += cnt[e]; }
    offp[NEXP] = s;
  }
}

__global__ void scatter_kernel(const int* __restrict__ tokp, const float2* __restrict__ tokw,
                               const int* __restrict__ offp, int* __restrict__ cursor,
                               int* __restrict__ btok, float* __restrict__ bw,
                               int* __restrict__ t2r) {
  int t = blockIdx.x * blockDim.x + threadIdx.x;
  if (t >= NTOK) return;
  int p = tokp[t];
  float2 w = tokw[t];
  int e0 = p & 0xff, e1 = (p >> 8) & 0xff;
  int r0 = offp[e0] + atomicAdd(&cursor[e0], 1);
  btok[r0] = t; bw[r0] = w.x; t2r[2 * t] = r0;
  int r1 = offp[e1] + atomicAdd(&cursor[e1], 1);
  btok[r1] = t; bw[r1] = w.y; t2r[2 * t + 1] = r1;
}

__global__ void combine_kernel(const _Float16* __restrict__ y2, const int* __restrict__ t2r,
                               const float2* __restrict__ tokw, float* __restrict__ out) {
  int idx = blockIdx.x * 256 + threadIdx.x;      // 4096 * 512
  int t = idx >> 9, c = (idx & 511) * 4;
  int r0 = t2r[2 * t], r1 = t2r[2 * t + 1];
  float2 w = tokw[t];
  half4v v0 = *(const half4v*)(y2 + (size_t)r0 * HDIM + c);
  half4v v1 = *(const half4v*)(y2 + (size_t)r1 * HDIM + c);
  float4 o;
  o.x = w.x * (float)v0[0] + w.y * (float)v1[0];
  o.y = w.x * (float)v0[1] + w.y * (float)v1[1];
  o.z = w.x * (float)v0[2] + w.y * (float)v1[2];
  o.w = w.x * (float)v0[3] + w.y * (float)v1[3];
  *(float4*)(out + (size_t)t * HDIM + c) = o;
}

// ---------------- stage 1: h = silu(X Wg^T) * (X Wu^T)  [r10 fused-B form] ----------------
// BM=128, B-rows=128 (64 Wg + 64 Wu), BK=32, 4 waves (2Mx2N), dbuf fp16 LDS (32 KB).
// A via global_load_lds (fp16); B streamed fp32 -> reg -> cvt -> ds_write (T14 split).
__global__ __launch_bounds__(256, 3) void stage1_kernel(
    const _Float16* __restrict__ xh, const float* __restrict__ Wg, const float* __restrict__ Wu,
    const int* __restrict__ offp, const int* __restrict__ btok, _Float16* __restrict__ hb) {
  int bid = blockIdx.x;
  int wg = (bid & 7) * (NWG1 / 8) + (bid >> 3);    // bijective: XCD k <-> expert k
  int rt = wg % NRT1;
  int ct = (wg / NRT1) % NCT1;
  int e  = wg / (NRT1 * NCT1);
  int base = offp[e];
  int ne = offp[e + 1] - base;
  if (rt * 128 >= ne) return;
  int valid = ne - rt * 128; if (valid > 128) valid = 128;
  int tid = threadIdx.x, lane = tid & 63, wave = tid >> 6;

  __shared__ __attribute__((aligned(16))) _Float16 As[2][128 * 32];   // 2 x 8 KB
  __shared__ __attribute__((aligned(16))) _Float16 Bs[2][128 * 32];   // 2 x 8 KB

  const char* abase = (const char*)xh;
  uint32_t aoffB[2];
  const float* bsrc[2];
  int bdstB[2];
  size_t eoff = (size_t)e * IDIM * HDIM;
#pragma unroll
  for (int i = 0; i < 2; ++i) {
    int L = wave * 128 + i * 64 + lane;
    int u = L >> 3, sc = (L & 7) ^ (u & 7);
    int r = 2 * u + (sc >> 2), q = sc & 3;
    int rr = (r < valid) ? r : (valid - 1);
    aoffB[i] = (uint32_t)(((uint32_t)btok[base + rt * 128 + rr] * HDIM + q * 8) * 2);
    const float* rp = (r < 64) ? (Wg + eoff + (size_t)(ct * 64 + r) * HDIM)
                               : (Wu + eoff + (size_t)(ct * 64 + (r - 64)) * HDIM);
    bsrc[i] = rp + q * 8;            // 8 floats -> one 16B fp16 chunk
    bdstB[i] = L * 16;
  }
  int adst0 = __builtin_amdgcn_readfirstlane(wave * 2048);

  int wm = wave >> 1, wn = wave & 1;
  int lrow = lane & 15, kg = lane >> 4;

  int aoff[4], boff[4];
#pragma unroll
  for (int mi = 0; mi < 4; ++mi) {
    int r = wm * 64 + mi * 16 + lrow;
    int u = r >> 1, cc = (r & 1) * 4 + kg;
    aoff[mi] = u * 64 + ((cc ^ (u & 7)) * 8);
  }
#pragma unroll
  for (int f = 0; f < 4; ++f) {
    int rb = (f < 2) ? (wn * 32 + f * 16 + lrow) : (64 + wn * 32 + (f - 2) * 16 + lrow);
    int u = rb >> 1, cc = (rb & 1) * 4 + kg;
    boff[f] = u * 64 + ((cc ^ (u & 7)) * 8);
  }

  floatx4 acc[4][4] = {};   // [mi][f]: f 0-1 = gate, 2-3 = up
  floatx4 bp[2][2];

  auto bload = [&](int t) {
#pragma unroll
    for (int i = 0; i < 2; ++i) {
      bp[i][0] = *(const floatx4*)(bsrc[i] + t * 32);
      bp[i][1] = *(const floatx4*)(bsrc[i] + t * 32 + 4);
    }
  };
  auto astage = [&](int t, int buf) {
    uint32_t kb = (uint32_t)t * 64u;
#pragma unroll
    for (int i = 0; i < 2; ++i)
      GLOAD16(abase + (aoffB[i] + kb), (char*)As[buf] + adst0 + i * 1024);
  };
  auto bwrite = [&](int buf) {
#pragma unroll
    for (int i = 0; i < 2; ++i) {
      half8 h = { (_Float16)bp[i][0].x, (_Float16)bp[i][0].y, (_Float16)bp[i][0].z, (_Float16)bp[i][0].w,
                  (_Float16)bp[i][1].x, (_Float16)bp[i][1].y, (_Float16)bp[i][1].z, (_Float16)bp[i][1].w };
      *(half8*)((char*)Bs[buf] + bdstB[i]) = h;
    }
  };
  auto compute = [&](int buf) {
    half8 af[4], bf[4];
#pragma unroll
    for (int mi = 0; mi < 4; ++mi) af[mi] = *(const half8*)&As[buf][aoff[mi]];
#pragma unroll
    for (int f = 0; f < 4; ++f) bf[f] = *(const half8*)&Bs[buf][boff[f]];
#pragma unroll
    for (int mi = 0; mi < 4; ++mi)
#pragma unroll
      for (int f = 0; f < 4; ++f)
        acc[mi][f] = __builtin_amdgcn_mfma_f32_16x16x32_f16(af[mi], bf[f], acc[mi][f], 0, 0, 0);
  };

  int cur = 0;
  bload(0);
  astage(0, 0);
  bwrite(0);
  __syncthreads();
#pragma unroll 2
  for (int t = 0; t < NK1 - 1; ++t) {
    bload(t + 1);            // fp32 B loads issued first: land during compute
    astage(t + 1, cur ^ 1);  // A DMA
    compute(cur);
    bwrite(cur ^ 1);         // cvt + ds_write after compute (T14 write-late)
    __syncthreads();
    cur ^= 1;
  }
  compute(cur);

  size_t hrow_base = (size_t)(base + rt * 128);
#pragma unroll
  for (int mi = 0; mi < 4; ++mi) {
#pragma unroll
    for (int j = 0; j < 4; ++j) {
      int r = wm * 64 + mi * 16 + kg * 4 + j;   // C/D: row=(lane>>4)*4+reg, col=lane&15
      if (r < valid) {
#pragma unroll
        for (int f = 0; f < 2; ++f) {
          float g = acc[mi][f][j], u = acc[mi][f + 2][j];
          float hv = g / (1.f + __expf(-g)) * u;   // silu(g)*u
          int c = ct * 64 + wn * 32 + f * 16 + lrow;
          hb[(hrow_base + r) * IDIM + c] = (_Float16)hv;
        }
      }
    }
  }
}

// ---------------- stage 2: y = h Wd^T  [r9 pre-converted form] ----------------
// BM=128, BN=128, BK=32, both operands via global_load_lds (fp16).
__global__ __launch_bounds__(256, 3) void stage2_kernel(
    const _Float16* __restrict__ hb, const _Float16* __restrict__ Wd16,
    const int* __restrict__ offp, _Float16* __restrict__ y2) {
  int bid = blockIdx.x;
  int wg = (bid & 7) * (NWG2 / 8) + (bid >> 3);
  int rt = wg % NRT2;
  int ct = (wg / NRT2) % NCT2;
  int e  = wg / (NRT2 * NCT2);
  int base = offp[e];
  int ne = offp[e + 1] - base;
  if (rt * 128 >= ne) return;
  int valid = ne - rt * 128; if (valid > 128) valid = 128;
  int tid = threadIdx.x, lane = tid & 63, wave = tid >> 6;

  __shared__ __attribute__((aligned(16))) _Float16 As[2][128 * 32];
  __shared__ __attribute__((aligned(16))) _Float16 Bs[2][128 * 32];

  const char* abase = (const char*)hb;
  const char* bbase = (const char*)(Wd16 + (size_t)e * HDIM * IDIM);

  uint32_t aoffB[2], boffB[2];
#pragma unroll
  for (int i = 0; i < 2; ++i) {
    int L = wave * 128 + i * 64 + lane;
    int u = L >> 3, sc = (L & 7) ^ (u & 7);
    int r = 2 * u + (sc >> 2), q = sc & 3;
    int rr = (r < valid) ? r : (valid - 1);
    aoffB[i] = (uint32_t)(((size_t)(base + rt * 128 + rr) * IDIM + (size_t)q * 8) * 2);
    boffB[i] = (uint32_t)(((size_t)(ct * 128 + r) * IDIM + (size_t)q * 8) * 2);
  }
  int adst0 = __builtin_amdgcn_readfirstlane(wave * 2048);

  int wm = wave >> 1, wn = wave & 1;
  int lrow = lane & 15, kg = lane >> 4;

  int aoff[4], boff[4];
#pragma unroll
  for (int mi = 0; mi < 4; ++mi) {
    int r = wm * 64 + mi * 16 + lrow;
    int u = r >> 1, cc = (r & 1) * 4 + kg;
    aoff[mi] = u * 64 + ((cc ^ (u & 7)) * 8);
  }
#pragma unroll
  for (int f = 0; f < 4; ++f) {
    int rb = wn * 64 + f * 16 + lrow;
    int u = rb >> 1, cc = (rb & 1) * 4 + kg;
    boff[f] = u * 64 + ((cc ^ (u & 7)) * 8);
  }

  floatx4 acc[4][4] = {};

  auto stage = [&](int t, int buf) {
    uint32_t kb = (uint32_t)t * 64u;
#pragma unroll
    for (int i = 0; i < 2; ++i) {
      GLOAD16(abase + (aoffB[i] + kb), (char*)As[buf] + adst0 + i * 1024);
      GLOAD16(bbase + (boffB[i] + kb), (char*)Bs[buf] + adst0 + i * 1024);
    }
  };
  auto compute = [&](int buf) {
    half8 af[4], bf[4];
#pragma unroll
    for (int mi = 0; mi < 4; ++mi) af[mi] = *(const half8*)&As[buf][aoff[mi]];
#pragma unroll
    for (int f = 0; f < 4; ++f) bf[f] = *(const half8*)&Bs[buf][boff[f]];
#pragma unroll
    for (int mi = 0; mi < 4; ++mi)
#pragma unroll
      for (int f = 0; f < 4; ++f)
        acc[mi][f] = __builtin_amdgcn_mfma_f32_16x16x32_f16(af[mi], bf[f], acc[mi][f], 0, 0, 0);
  };

  int cur = 0;
  stage(0, 0);
  __syncthreads();
#pragma unroll 2
  for (int t = 0; t < NK2 - 1; ++t) {
    stage(t + 1, cur ^ 1);
    compute(cur);
    __syncthreads();
    cur ^= 1;
  }
  compute(cur);

#pragma unroll
  for (int mi = 0; mi < 4; ++mi) {
#pragma unroll
    for (int j = 0; j < 4; ++j) {
      int r = wm * 64 + mi * 16 + kg * 4 + j;
      if (r < valid) {
        int grow = base + rt * 128 + r;
#pragma unroll
        for (int f = 0; f < 4; ++f) {
          int c = ct * 128 + wn * 64 + f * 16 + lrow;
          y2[(size_t)grow * HDIM + c] = (_Float16)acc[mi][f][j];
        }
      }
    }
  }
}

// ---------------- launch ----------------
extern "C" void kernel_launch(void* const* d_in, const int* in_sizes, int n_in,
                              void* d_out, int out_size, void* d_ws, size_t ws_size,
                              hipStream_t stream) {
  const float* x  = (const float*)d_in[0];
  const float* rw = (const float*)d_in[1];
  const float* Wg = (const float*)d_in[2];
  const float* Wu = (const float*)d_in[3];
  const float* Wd = (const float*)d_in[4];
  float* out = (float*)d_out;

  char* ws = (char*)d_ws;
  _Float16* xh  = (_Float16*)(ws + XH_OFF);
  _Float16* hb  = (_Float16*)(ws + HB_OFF);
  int*      btok = (int*)(ws + BTOK_OFF);
  float*    bwv  = (float*)(ws + BW_OFF);
  int*      tokp = (int*)(ws + TOKP_OFF);
  float2*   tokw = (float2*)(ws + TOKW_OFF);
  int*      t2r  = (int*)(ws + T2R_OFF);
  int*      meta = (int*)(ws + META_OFF);
  _Float16* y2   = (_Float16*)(ws + Y2_OFF);
  _Float16* wd16 = (_Float16*)(ws + WD16_OFF);
  int* cnt = meta;          // [8]
  int* offp = meta + 8;     // [9]
  int* cursor = meta + 20;  // [8]

  hipMemsetAsync(meta, 0, 128, stream);

  router_kernel<<<NTOK / 4, 256, 0, stream>>>(x, rw, xh, tokp, tokw, cnt);
  scan_kernel<<<1, 64, 0, stream>>>(cnt, offp);
  scatter_kernel<<<NTOK / 256, 256, 0, stream>>>(tokp, tokw, offp, cursor, btok, bwv, t2r);
  cvt_w_kernel<<<2048, 256, 0, stream>>>((const float4*)Wd, (half8*)wd16,
                                         NEXP * HDIM * IDIM / 8);

  stage1_kernel<<<NWG1, 256, 0, stream>>>(xh, Wg, Wu, offp, btok, hb);
  stage2_kernel<<<NWG2, 256, 0, stream>>>(hb, wd16, offp, y2);
  combine_kernel<<<NTOK * HDIM / 4 / 256, 256, 0, stream>>>(y2, t2r, tokw, out);
}